// Round 1
// baseline (1062.893 us; speedup 1.0000x reference)
//
#include <hip/hip_runtime.h>
#include <hip/hip_bf16.h>

#define M_DIM 8192
#define K_DIM 4096
#define N_DIM 11008

typedef short s16x8 __attribute__((ext_vector_type(8)));   // 8 bf16 (4 VGPR) MFMA operand
typedef float f32x4 __attribute__((ext_vector_type(4)));   // MFMA accumulator

__device__ __forceinline__ unsigned int f2bf(float f) {
    unsigned int u = __float_as_uint(f);
    u += 0x7FFFu + ((u >> 16) & 1u);   // round-to-nearest-even (no NaNs in this data)
    return u >> 16;
}

// ---------- pre-pass 1: x fp32 -> bf16, 8 elems/thread ----------
__global__ __launch_bounds__(256) void k_cvt_x(const float4* __restrict__ x, uint4* __restrict__ xb) {
    int i = blockIdx.x * 256 + threadIdx.x;          // one uint4 (8 bf16) per thread
    float4 a = x[i * 2], b = x[i * 2 + 1];
    uint4 o;
    o.x = f2bf(a.x) | (f2bf(a.y) << 16);
    o.y = f2bf(a.z) | (f2bf(a.w) << 16);
    o.z = f2bf(b.x) | (f2bf(b.y) << 16);
    o.w = f2bf(b.z) | (f2bf(b.w) << 16);
    xb[i] = o;
}

// ---------- pre-pass 2: dequant q int32 -> bf16, 8 elems/thread ----------
__global__ __launch_bounds__(256) void k_deq(const int4* __restrict__ q, const float* __restrict__ sc,
                                             const float* __restrict__ zp, uint4* __restrict__ wb) {
    int i = blockIdx.x * 256 + threadIdx.x;          // 8 elems per thread
    int o = i >> 9;                                  // (i*8)/4096 : output channel
    float s = sc[o], z = zp[o];
    int4 a = q[i * 2], b = q[i * 2 + 1];
    uint4 r;
    r.x = f2bf(((float)a.x - z) * s) | (f2bf(((float)a.y - z) * s) << 16);
    r.y = f2bf(((float)a.z - z) * s) | (f2bf(((float)a.w - z) * s) << 16);
    r.z = f2bf(((float)b.x - z) * s) | (f2bf(((float)b.y - z) * s) << 16);
    r.w = f2bf(((float)b.z - z) * s) | (f2bf(((float)b.w - z) * s) << 16);
    wb[i] = r;
}

// ---------- main GEMM: C[m][n] = sum_k A[m][k]*B[n][k] + bias[n] ----------
// m97 structure: 128x128 tile, BK=64, 4 waves (2x2), single LDS buffer,
// global_load_lds width=16 staging, 16x16x32 bf16 MFMA, 4x4 frags/wave.
using gcptr = const __attribute__((address_space(1))) void*;
using lptr  = __attribute__((address_space(3))) void*;
#define GLD16(gp, lp) __builtin_amdgcn_global_load_lds((gcptr)(gp), (lptr)(lp), 16, 0, 0)

__global__ __launch_bounds__(256) void k_gemm(const unsigned short* __restrict__ A,
                                              const unsigned short* __restrict__ B,
                                              const float* __restrict__ bias,
                                              float* __restrict__ C) {
    constexpr int BM = 128, BN = 128, BK = 64;
    constexpr int NBM = M_DIM / BM;                 // 64
    constexpr int NWG = (M_DIM / BM) * (N_DIM / BN); // 5504 (divisible by 8)

    // XCD-aware bijective swizzle (nwg % 8 == 0)
    int orig = blockIdx.x;
    int id = (orig & 7) * (NWG / 8) + (orig >> 3);
    int bm = id % NBM;
    int bn = id / NBM;

    int tid = threadIdx.x;
    int lane = tid & 63;
    int w = tid >> 6;          // wave 0..3
    int wr = w >> 1, wc = w & 1;

    __shared__ alignas(16) unsigned short sA[BM * BK];   // [128][64] bf16, 16 KB
    __shared__ alignas(16) unsigned short sB[BN * BK];

    const int rowA0 = bm * BM;
    const int rowB0 = bn * BN;

    // staging: wave w owns chunks 4w..4w+3 (1 KB each = 8 rows of 64 bf16)
    const unsigned short* aSrc = A + (rowA0 + 32 * w + (lane >> 3)) * K_DIM + (lane & 7) * 8;
    const unsigned short* bSrc = B + (rowB0 + 32 * w + (lane >> 3)) * K_DIM + (lane & 7) * 8;
    unsigned short* sAb = &sA[(w * 4) * 512];
    unsigned short* sBb = &sB[(w * 4) * 512];

    f32x4 acc[4][4];
#pragma unroll
    for (int i = 0; i < 4; ++i)
#pragma unroll
        for (int j = 0; j < 4; ++j) acc[i][j] = (f32x4){0.f, 0.f, 0.f, 0.f};

    for (int kt = 0; kt < K_DIM / BK; ++kt) {
        __syncthreads();                       // all reads of previous tile done
        const int k0 = kt * BK;
#pragma unroll
        for (int cc = 0; cc < 4; ++cc) {
            GLD16(aSrc + k0 + cc * 8 * K_DIM, sAb + cc * 512);
            GLD16(bSrc + k0 + cc * 8 * K_DIM, sBb + cc * 512);
        }
        asm volatile("s_waitcnt vmcnt(0)" ::: "memory");
        __syncthreads();                       // tile staged

#pragma unroll
        for (int kk = 0; kk < 2; ++kk) {
            s16x8 af[4], bfr[4];
#pragma unroll
            for (int mi = 0; mi < 4; ++mi)
                af[mi] = *(const s16x8*)&sA[(wr * 64 + mi * 16 + (lane & 15)) * BK + kk * 32 + (lane >> 4) * 8];
#pragma unroll
            for (int ni = 0; ni < 4; ++ni)
                bfr[ni] = *(const s16x8*)&sB[(wc * 64 + ni * 16 + (lane & 15)) * BK + kk * 32 + (lane >> 4) * 8];
#pragma unroll
            for (int mi = 0; mi < 4; ++mi)
#pragma unroll
                for (int ni = 0; ni < 4; ++ni)
                    acc[mi][ni] = __builtin_amdgcn_mfma_f32_16x16x32_bf16(af[mi], bfr[ni], acc[mi][ni], 0, 0, 0);
        }
    }

    // epilogue: C[row][col] = acc + bias[col]
#pragma unroll
    for (int ni = 0; ni < 4; ++ni) {
        int col = rowB0 + wc * 64 + ni * 16 + (lane & 15);
        float bv = bias[col];
#pragma unroll
        for (int mi = 0; mi < 4; ++mi) {
            int row = rowA0 + wr * 64 + mi * 16 + (lane >> 4) * 4;
            float* cp = C + (size_t)row * N_DIM + col;
#pragma unroll
            for (int j = 0; j < 4; ++j)
                cp[(size_t)j * N_DIM] = acc[mi][ni][j] + bv;
        }
    }
}

// ---------- fallback (ws too small): classic 16x16 fp32 tiled GEMM ----------
__global__ __launch_bounds__(256) void k_fb(const float* __restrict__ x, const int* __restrict__ q,
                                            const float* __restrict__ sc, const float* __restrict__ zp,
                                            const float* __restrict__ bias, float* __restrict__ C) {
    __shared__ float sX[16][17];
    __shared__ float sW[16][17];
    int tx = threadIdx.x & 15, ty = threadIdx.x >> 4;
    int m0 = blockIdx.y * 16, n0 = blockIdx.x * 16;
    int o = n0 + ty;
    float s = sc[o], z = zp[o];
    float acc = 0.f;
    for (int k0 = 0; k0 < K_DIM; k0 += 16) {
        sX[ty][tx] = x[(size_t)(m0 + ty) * K_DIM + k0 + tx];
        sW[ty][tx] = ((float)q[(size_t)o * K_DIM + k0 + tx] - z) * s;
        __syncthreads();
#pragma unroll
        for (int kk = 0; kk < 16; ++kk) acc += sX[ty][kk] * sW[tx][kk];
        __syncthreads();
    }
    C[(size_t)(m0 + ty) * N_DIM + n0 + tx] = acc + bias[n0 + tx];
}

extern "C" void kernel_launch(void* const* d_in, const int* in_sizes, int n_in,
                              void* d_out, int out_size, void* d_ws, size_t ws_size,
                              hipStream_t stream) {
    const float* x    = (const float*)d_in[0];
    const int*   qw   = (const int*)d_in[1];
    const float* sc   = (const float*)d_in[2];
    const float* zp   = (const float*)d_in[3];
    const float* bias = (const float*)d_in[4];
    float* out = (float*)d_out;

    const size_t xb_bytes = (size_t)M_DIM * K_DIM * 2;   // 67,108,864
    const size_t wb_bytes = (size_t)N_DIM * K_DIM * 2;   // 90,177,536
    if (ws_size >= xb_bytes + wb_bytes) {
        unsigned short* xb = (unsigned short*)d_ws;
        unsigned short* wb = xb + (size_t)M_DIM * K_DIM;
        k_cvt_x<<<(M_DIM * K_DIM / 8) / 256, 256, 0, stream>>>((const float4*)x, (uint4*)xb);
        k_deq<<<(N_DIM * K_DIM / 8) / 256, 256, 0, stream>>>((const int4*)qw, sc, zp, (uint4*)wb);
        k_gemm<<<(M_DIM / 128) * (N_DIM / 128), 256, 0, stream>>>(xb, wb, bias, out);
    } else {
        dim3 g(N_DIM / 16, M_DIM / 16);
        k_fb<<<g, 256, 0, stream>>>(x, qw, sc, zp, bias, out);
    }
}

// Round 2
// 917.218 us; speedup vs baseline: 1.1588x; 1.1588x over previous
//
#include <hip/hip_runtime.h>
#include <hip/hip_bf16.h>

#define M_DIM 8192
#define K_DIM 4096
#define N_DIM 11008

typedef unsigned short ushort_t;
typedef short s16x8 __attribute__((ext_vector_type(8)));   // 8 bf16 (4 VGPR) MFMA operand
typedef float f32x4 __attribute__((ext_vector_type(4)));   // MFMA accumulator

__device__ __forceinline__ unsigned int f2bf(float f) {
    unsigned int u = __float_as_uint(f);
    u += 0x7FFFu + ((u >> 16) & 1u);   // round-to-nearest-even
    return u >> 16;
}

// ---------- pre-pass 1: x fp32 -> bf16 ----------
__global__ __launch_bounds__(256) void k_cvt_x(const float4* __restrict__ x, uint4* __restrict__ xb) {
    int i = blockIdx.x * 256 + threadIdx.x;
    float4 a = x[i * 2], b = x[i * 2 + 1];
    uint4 o;
    o.x = f2bf(a.x) | (f2bf(a.y) << 16);
    o.y = f2bf(a.z) | (f2bf(a.w) << 16);
    o.z = f2bf(b.x) | (f2bf(b.y) << 16);
    o.w = f2bf(b.z) | (f2bf(b.w) << 16);
    xb[i] = o;
}

// ---------- pre-pass 2: dequant q int32 -> bf16 ----------
__global__ __launch_bounds__(256) void k_deq(const int4* __restrict__ q, const float* __restrict__ sc,
                                             const float* __restrict__ zp, uint4* __restrict__ wb) {
    int i = blockIdx.x * 256 + threadIdx.x;
    int o = i >> 9;
    float s = sc[o], z = zp[o];
    int4 a = q[i * 2], b = q[i * 2 + 1];
    uint4 r;
    r.x = f2bf(((float)a.x - z) * s) | (f2bf(((float)a.y - z) * s) << 16);
    r.y = f2bf(((float)a.z - z) * s) | (f2bf(((float)a.w - z) * s) << 16);
    r.z = f2bf(((float)b.x - z) * s) | (f2bf(((float)b.y - z) * s) << 16);
    r.w = f2bf(((float)b.z - z) * s) | (f2bf(((float)b.w - z) * s) << 16);
    wb[i] = r;
}

// ---------- 256x256 8-phase GEMM: C[m][n] = sum_k A[m][k]*B[n][k] + bias[n] ----------
using gcptr = const __attribute__((address_space(1))) void*;
using lptr  = __attribute__((address_space(3))) void*;
#define GLD16(gp, lp) __builtin_amdgcn_global_load_lds((gcptr)(gp), (lptr)(lp), 16, 0, 0)
#define BAR() asm volatile("s_barrier" ::: "memory")
#define VMW4() asm volatile("s_waitcnt vmcnt(4)" ::: "memory")
#define VMW0() asm volatile("s_waitcnt vmcnt(0)" ::: "memory")

__global__ __launch_bounds__(512, 2) void k_gemm(const ushort_t* __restrict__ A,
                                                 const ushort_t* __restrict__ B,
                                                 const float* __restrict__ bias,
                                                 float* __restrict__ C) {
    constexpr int NT = K_DIM / 64;              // 64 K-tiles of BK=64
    constexpr int NBM = M_DIM / 256;            // 32
    constexpr int NWG = NBM * (N_DIM / 256);    // 1376, % 8 == 0

    __shared__ ushort_t sA[2][256 * 64];        // 2 x 32 KB
    __shared__ ushort_t sB[2][256 * 64];        // 2 x 32 KB  (128 KB total)

    // XCD-aware bijective swizzle
    int id = (blockIdx.x & 7) * (NWG / 8) + (blockIdx.x >> 3);
    const int bm = id & (NBM - 1);
    const int bn = id >> 5;

    const int tid = threadIdx.x;
    const int lane = tid & 63;
    const int w  = tid >> 6;     // wave 0..7
    const int wr = w >> 2;       // 0..1 (M)
    const int wc = w & 3;        // 0..3 (N)

    // ---- staging source (pre-swizzled global col so linear LDS dest == swizzled layout) ----
    const int trow = tid >> 3;                                   // 0..63
    const int scol = ((tid & 7) * 8) ^ (((tid >> 5) & 1) * 16);  // st_16x32 pre-swizzle
    const ushort_t* aBase = A + (size_t)(bm * 256 + trow) * K_DIM + scol;
    const ushort_t* bBase = B + (size_t)(bn * 256 + trow) * K_DIM + scol;
    const int ldsW = w * 512;                                    // wave-uniform dest (ushorts)

    // stage half H (128 rows) of K-tile kt into compile-time buffer sbuf (2 x GLD16/wave)
#define STAGE_A(kt, H, sbuf) do { if ((kt) < NT) { \
        const ushort_t* _s = aBase + (size_t)((H) * 128) * K_DIM + (kt) * 64; \
        ushort_t* _d = &sA[sbuf][(H) * 8192 + ldsW]; \
        GLD16(_s, _d); GLD16(_s + (size_t)64 * K_DIM, _d + 4096); } } while (0)
#define STAGE_B(kt, H, sbuf) do { if ((kt) < NT) { \
        const ushort_t* _s = bBase + (size_t)((H) * 128) * K_DIM + (kt) * 64; \
        ushort_t* _d = &sB[sbuf][(H) * 8192 + ldsW]; \
        GLD16(_s, _d); GLD16(_s + (size_t)64 * K_DIM, _d + 4096); } } while (0)

    // ---- ds_read lane bases (swizzled), in ushorts ----
    const int cAe = ((lane >> 4) * 8) ^ (((lane >> 2) & 1) * 16);
    const int laneAe = wr * 1024 + (lane & 15) * 64 + cAe;
    const int laneBe = wc * 1024 + (lane & 15) * 64 + cAe;

    s16x8 aF[4][2], bF[2][2];
    f32x4 acc[8][4];
#pragma unroll
    for (int j = 0; j < 8; ++j)
#pragma unroll
        for (int i = 0; i < 4; ++i) acc[j][i] = (f32x4){0.f, 0.f, 0.f, 0.f};

#define LDA(mh, buf) do { \
    _Pragma("unroll") for (int jj = 0; jj < 4; ++jj) \
    _Pragma("unroll") for (int kk = 0; kk < 2; ++kk) \
        aF[jj][kk] = *(const s16x8*)&sA[buf][(mh) * 8192 + jj * 2048 + kk * 32 + laneAe]; \
    } while (0)
#define LDB(nh, buf) do { \
    _Pragma("unroll") for (int ii = 0; ii < 2; ++ii) \
    _Pragma("unroll") for (int kk = 0; kk < 2; ++kk) \
        bF[ii][kk] = *(const s16x8*)&sB[buf][(nh) * 8192 + ii * 4096 + kk * 32 + laneBe]; \
    } while (0)
#define MFMA_Q(mh, nh) do { \
    __builtin_amdgcn_s_setprio(1); \
    _Pragma("unroll") for (int jj = 0; jj < 4; ++jj) \
    _Pragma("unroll") for (int ii = 0; ii < 2; ++ii) \
    _Pragma("unroll") for (int kk = 0; kk < 2; ++kk) \
        acc[(mh) * 4 + jj][(nh) * 2 + ii] = __builtin_amdgcn_mfma_f32_16x16x32_bf16( \
            aF[jj][kk], bF[ii][kk], acc[(mh) * 4 + jj][(nh) * 2 + ii], 0, 0, 0); \
    __builtin_amdgcn_s_setprio(0); \
    } while (0)

    // ---- prologue: stage K-tile 0 fully + B0/A1 of K-tile 1 (steady-state issue order) ----
    STAGE_B(0, 0, 0);
    STAGE_A(0, 1, 0);
    STAGE_A(0, 0, 0);
    STAGE_B(0, 1, 0);
    STAGE_B(1, 0, 1);
    STAGE_A(1, 1, 1);
    VMW4();          // all of K-tile 0 landed; B0(1)/A1(1) in flight
    BAR();

    // ---- main loop: 8 phases / iteration, 2 K-tiles / iteration ----
    // phase order (mh,nh): (0,0) (1,0) (1,1) (0,1)
    // stages:        P1: A0(g+1)  P2: B1(g+1)  P3: B0(g+2)  P4: A1(g+2)
#define GROUP(g, buf) do { \
        /* P1 */ LDA(0, buf); LDB(0, buf); STAGE_A((g) + 1, 0, (buf) ^ 1); \
                 BAR(); MFMA_Q(0, 0); BAR(); \
        /* P2 */ LDA(1, buf);             STAGE_B((g) + 1, 1, (buf) ^ 1); \
                 BAR(); MFMA_Q(1, 0); BAR(); \
        /* P3 */ LDB(1, buf);             STAGE_B((g) + 2, 0, buf); \
                 BAR(); MFMA_Q(1, 1); BAR(); \
        /* P4 */ LDA(0, buf);             STAGE_A((g) + 2, 1, buf); \
                 BAR(); MFMA_Q(0, 1); \
                 if ((g) >= NT - 2) { VMW0(); } else { VMW4(); } \
                 BAR(); \
    } while (0)

    for (int g = 0; g < NT; g += 2) {
        GROUP(g, 0);
        GROUP(g + 1, 1);
    }

    // ---- epilogue: C += bias ----
    // m-frag j -> rows bm*256 + 16*wr + 32*j (+ (lane>>4)*4 + r)
    // n-frag i -> cols bn*256 + 16*wc + 64*i (+ (lane&15))
#pragma unroll
    for (int i = 0; i < 4; ++i) {
        const int col = bn * 256 + 16 * wc + 64 * i + (lane & 15);
        const float bv = bias[col];
#pragma unroll
        for (int j = 0; j < 8; ++j) {
            const int row = bm * 256 + 16 * wr + 32 * j + ((lane >> 4) << 2);
            float* cp = C + (size_t)row * N_DIM + col;
#pragma unroll
            for (int r = 0; r < 4; ++r)
                cp[(size_t)r * N_DIM] = acc[j][i][r] + bv;
        }
    }
#undef GROUP
#undef MFMA_Q
#undef LDA
#undef LDB
#undef STAGE_A
#undef STAGE_B
}

// ---------- fallback (ws too small): classic 16x16 fp32 tiled GEMM ----------
__global__ __launch_bounds__(256) void k_fb(const float* __restrict__ x, const int* __restrict__ q,
                                            const float* __restrict__ sc, const float* __restrict__ zp,
                                            const float* __restrict__ bias, float* __restrict__ C) {
    __shared__ float sX[16][17];
    __shared__ float sW[16][17];
    int tx = threadIdx.x & 15, ty = threadIdx.x >> 4;
    int m0 = blockIdx.y * 16, n0 = blockIdx.x * 16;
    int o = n0 + ty;
    float s = sc[o], z = zp[o];
    float acc = 0.f;
    for (int k0 = 0; k0 < K_DIM; k0 += 16) {
        sX[ty][tx] = x[(size_t)(m0 + ty) * K_DIM + k0 + tx];
        sW[ty][tx] = ((float)q[(size_t)o * K_DIM + k0 + tx] - z) * s;
        __syncthreads();
#pragma unroll
        for (int kk = 0; kk < 16; ++kk) acc += sX[ty][kk] * sW[tx][kk];
        __syncthreads();
    }
    C[(size_t)(m0 + ty) * N_DIM + n0 + tx] = acc + bias[n0 + tx];
}

extern "C" void kernel_launch(void* const* d_in, const int* in_sizes, int n_in,
                              void* d_out, int out_size, void* d_ws, size_t ws_size,
                              hipStream_t stream) {
    const float* x    = (const float*)d_in[0];
    const int*   qw   = (const int*)d_in[1];
    const float* sc   = (const float*)d_in[2];
    const float* zp   = (const float*)d_in[3];
    const float* bias = (const float*)d_in[4];
    float* out = (float*)d_out;

    const size_t xb_bytes = (size_t)M_DIM * K_DIM * 2;
    const size_t wb_bytes = (size_t)N_DIM * K_DIM * 2;
    if (ws_size >= xb_bytes + wb_bytes) {
        unsigned short* xb = (unsigned short*)d_ws;
        unsigned short* wb = xb + (size_t)M_DIM * K_DIM;
        k_cvt_x<<<(M_DIM * K_DIM / 8) / 256, 256, 0, stream>>>((const float4*)x, (uint4*)xb);
        k_deq<<<(N_DIM * K_DIM / 8) / 256, 256, 0, stream>>>((const int4*)qw, sc, zp, (uint4*)wb);
        k_gemm<<<(M_DIM / 256) * (N_DIM / 256), 512, 0, stream>>>(xb, wb, bias, out);
    } else {
        dim3 g(N_DIM / 16, M_DIM / 16);
        k_fb<<<g, 256, 0, stream>>>(x, qw, sc, zp, bias, out);
    }
}

// Round 3
// 836.656 us; speedup vs baseline: 1.2704x; 1.0963x over previous
//
#include <hip/hip_runtime.h>
#include <hip/hip_bf16.h>

#define M_DIM 8192
#define K_DIM 4096
#define N_DIM 11008

typedef unsigned short ushort_t;
typedef short s16x8 __attribute__((ext_vector_type(8)));   // 8 bf16 (4 VGPR) MFMA operand
typedef float f32x4 __attribute__((ext_vector_type(4)));   // MFMA accumulator

__device__ __forceinline__ unsigned int f2bf(float f) {
    unsigned int u = __float_as_uint(f);
    u += 0x7FFFu + ((u >> 16) & 1u);   // round-to-nearest-even
    return u >> 16;
}

// ---------- pre-pass 1: x fp32 -> bf16 ----------
__global__ __launch_bounds__(256) void k_cvt_x(const float4* __restrict__ x, uint4* __restrict__ xb) {
    int i = blockIdx.x * 256 + threadIdx.x;
    float4 a = x[i * 2], b = x[i * 2 + 1];
    uint4 o;
    o.x = f2bf(a.x) | (f2bf(a.y) << 16);
    o.y = f2bf(a.z) | (f2bf(a.w) << 16);
    o.z = f2bf(b.x) | (f2bf(b.y) << 16);
    o.w = f2bf(b.z) | (f2bf(b.w) << 16);
    xb[i] = o;
}

// ---------- pre-pass 2: dequant q int32 -> bf16 ----------
__global__ __launch_bounds__(256) void k_deq(const int4* __restrict__ q, const float* __restrict__ sc,
                                             const float* __restrict__ zp, uint4* __restrict__ wb) {
    int i = blockIdx.x * 256 + threadIdx.x;
    int o = i >> 9;
    float s = sc[o], z = zp[o];
    int4 a = q[i * 2], b = q[i * 2 + 1];
    uint4 r;
    r.x = f2bf(((float)a.x - z) * s) | (f2bf(((float)a.y - z) * s) << 16);
    r.y = f2bf(((float)a.z - z) * s) | (f2bf(((float)a.w - z) * s) << 16);
    r.z = f2bf(((float)b.x - z) * s) | (f2bf(((float)b.y - z) * s) << 16);
    r.w = f2bf(((float)b.z - z) * s) | (f2bf(((float)b.w - z) * s) << 16);
    wb[i] = r;
}

// ---------- 256x256 8-phase GEMM: C[m][n] = sum_k A[m][k]*B[n][k] + bias[n] ----------
// LDS swizzle: 16-byte chunk c of row r stores global chunk c ^ (r&7)
// (full XOR per G4: 16 same-column lanes -> 8 distinct 16B slots, 2-way = free)
using gcptr = const __attribute__((address_space(1))) void*;
using lptr  = __attribute__((address_space(3))) void*;
#define GLD16(gp, lp) __builtin_amdgcn_global_load_lds((gcptr)(gp), (lptr)(lp), 16, 0, 0)
#define BAR() asm volatile("s_barrier" ::: "memory")
#define VMW4() asm volatile("s_waitcnt vmcnt(4)" ::: "memory")
#define VMW0() asm volatile("s_waitcnt vmcnt(0)" ::: "memory")

__global__ __launch_bounds__(512, 2) void k_gemm(const ushort_t* __restrict__ A,
                                                 const ushort_t* __restrict__ B,
                                                 const float* __restrict__ bias,
                                                 float* __restrict__ C) {
    constexpr int NT = K_DIM / 64;              // 64 K-tiles of BK=64
    constexpr int NBM = M_DIM / 256;            // 32
    constexpr int NWG = NBM * (N_DIM / 256);    // 1376, % 8 == 0

    __shared__ ushort_t sA[2][256 * 64];        // 2 x 32 KB
    __shared__ ushort_t sB[2][256 * 64];        // 2 x 32 KB  (128 KB total)

    // XCD-aware bijective swizzle
    int id = (blockIdx.x & 7) * (NWG / 8) + (blockIdx.x >> 3);
    const int bm = id & (NBM - 1);
    const int bn = id >> 5;

    const int tid = threadIdx.x;
    const int lane = tid & 63;
    const int w  = tid >> 6;     // wave 0..7
    const int wr = w >> 2;       // 0..1 (M)
    const int wc = w & 3;        // 0..3 (N)

    // ---- staging source (pre-swizzled global chunk: c_src = c_lds ^ (row&7)) ----
    const int trow = tid >> 3;                                   // 0..63 (row within half, first 64)
    const int scol = ((tid & 7) ^ (trow & 7)) * 8;               // XOR-swizzled source col
    const ushort_t* aBase = A + (size_t)(bm * 256 + trow) * K_DIM + scol;
    const ushort_t* bBase = B + (size_t)(bn * 256 + trow) * K_DIM + scol;
    const int ldsW = w * 512;                                    // wave-uniform dest (ushorts)

    // stage half H (128 rows) of K-tile kt into buffer sbuf (2 x GLD16/wave)
#define STAGE_A(kt, H, sbuf) do { if ((kt) < NT) { \
        const ushort_t* _s = aBase + (size_t)((H) * 128) * K_DIM + (kt) * 64; \
        ushort_t* _d = &sA[sbuf][(H) * 8192 + ldsW]; \
        GLD16(_s, _d); GLD16(_s + (size_t)64 * K_DIM, _d + 4096); } } while (0)
#define STAGE_B(kt, H, sbuf) do { if ((kt) < NT) { \
        const ushort_t* _s = bBase + (size_t)((H) * 128) * K_DIM + (kt) * 64; \
        ushort_t* _d = &sB[sbuf][(H) * 8192 + ldsW]; \
        GLD16(_s, _d); GLD16(_s + (size_t)64 * K_DIM, _d + 4096); } } while (0)

    // ---- ds_read lane addressing (swizzled) ----
    const int rowAe = (wr * 16 + (lane & 15)) * 64;   // element offset of row within half
    const int rowBe = (wc * 16 + (lane & 15)) * 64;
    const int cb  = lane >> 4;                        // k-chunk base 0..3
    const int swz = lane & 7;                         // row&7 for this lane's rows

    s16x8 aF[4][2];          // current A-half: 4 m-frags x 2 kk
    s16x8 bF[2][2][2];       // BOTH B-halves resident: nh x 2 ii x 2 kk
    f32x4 acc[8][4];
#pragma unroll
    for (int j = 0; j < 8; ++j)
#pragma unroll
        for (int i = 0; i < 4; ++i) acc[j][i] = (f32x4){0.f, 0.f, 0.f, 0.f};

#define LDA(mh, buf) do { \
    _Pragma("unroll") for (int jj = 0; jj < 4; ++jj) \
    _Pragma("unroll") for (int kk = 0; kk < 2; ++kk) \
        aF[jj][kk] = *(const s16x8*)&sA[buf][(mh) * 8192 + jj * 2048 + rowAe + (((cb + kk * 4) ^ swz) * 8)]; \
    } while (0)
#define LDB(nh, buf) do { \
    _Pragma("unroll") for (int ii = 0; ii < 2; ++ii) \
    _Pragma("unroll") for (int kk = 0; kk < 2; ++kk) \
        bF[nh][ii][kk] = *(const s16x8*)&sB[buf][(nh) * 8192 + ii * 4096 + rowBe + (((cb + kk * 4) ^ swz) * 8)]; \
    } while (0)
#define MFMA_Q(mh, nh) do { \
    __builtin_amdgcn_s_setprio(1); \
    _Pragma("unroll") for (int jj = 0; jj < 4; ++jj) \
    _Pragma("unroll") for (int ii = 0; ii < 2; ++ii) \
    _Pragma("unroll") for (int kk = 0; kk < 2; ++kk) \
        acc[(mh) * 4 + jj][(nh) * 2 + ii] = __builtin_amdgcn_mfma_f32_16x16x32_bf16( \
            aF[jj][kk], bF[nh][ii][kk], acc[(mh) * 4 + jj][(nh) * 2 + ii], 0, 0, 0); \
    __builtin_amdgcn_s_setprio(0); \
    } while (0)

    // ---- prologue: tile 0 fully + B0/A1 of tile 1 (issued last -> vmcnt(4) keeps them in flight) ----
    STAGE_A(0, 0, 0);
    STAGE_B(0, 0, 0);
    STAGE_B(0, 1, 0);
    STAGE_A(0, 1, 0);
    STAGE_B(1, 0, 1);
    STAGE_A(1, 1, 1);
    VMW4();          // tile 0 landed; B0(1)/A1(1) in flight
    BAR();

    // ---- main loop: 4 phases / K-tile, each operand ds_read exactly once (24 b128/lane/tile) ----
    // phase order (mh,nh): (0,0) (0,1) (1,1) (1,0); both B-halves kept in regs through P4
    // stages:  P1: A0(g+1)  P2: B1(g+1)  P3: B0(g+2)  P4: A1(g+2)
#define GROUP(g, buf) do { \
        /* P1 */ LDA(0, buf); LDB(0, buf); STAGE_A((g) + 1, 0, (buf) ^ 1); \
                 BAR(); MFMA_Q(0, 0); BAR(); \
        /* P2 */ LDB(1, buf);             STAGE_B((g) + 1, 1, (buf) ^ 1); \
                 BAR(); MFMA_Q(0, 1); BAR(); \
        /* P3 */ LDA(1, buf);             STAGE_B((g) + 2, 0, buf); \
                 BAR(); MFMA_Q(1, 1); BAR(); \
        /* P4 */                          STAGE_A((g) + 2, 1, buf); \
                 BAR(); MFMA_Q(1, 0); \
                 if ((g) >= NT - 2) { VMW0(); } else { VMW4(); } \
                 BAR(); \
    } while (0)

    for (int g = 0; g < NT; g += 2) {
        GROUP(g, 0);
        GROUP(g + 1, 1);
    }

    // ---- epilogue: C += bias ----
#pragma unroll
    for (int i = 0; i < 4; ++i) {
        const int col = bn * 256 + 16 * wc + 64 * i + (lane & 15);
        const float bv = bias[col];
#pragma unroll
        for (int j = 0; j < 8; ++j) {
            const int row = bm * 256 + 16 * wr + 32 * j + ((lane >> 4) << 2);
            float* cp = C + (size_t)row * N_DIM + col;
#pragma unroll
            for (int r = 0; r < 4; ++r)
                cp[(size_t)r * N_DIM] = acc[j][i][r] + bv;
        }
    }
#undef GROUP
#undef MFMA_Q
#undef LDA
#undef LDB
#undef STAGE_A
#undef STAGE_B
}

// ---------- fallback (ws too small): classic 16x16 fp32 tiled GEMM ----------
__global__ __launch_bounds__(256) void k_fb(const float* __restrict__ x, const int* __restrict__ q,
                                            const float* __restrict__ sc, const float* __restrict__ zp,
                                            const float* __restrict__ bias, float* __restrict__ C) {
    __shared__ float sX[16][17];
    __shared__ float sW[16][17];
    int tx = threadIdx.x & 15, ty = threadIdx.x >> 4;
    int m0 = blockIdx.y * 16, n0 = blockIdx.x * 16;
    int o = n0 + ty;
    float s = sc[o], z = zp[o];
    float acc = 0.f;
    for (int k0 = 0; k0 < K_DIM; k0 += 16) {
        sX[ty][tx] = x[(size_t)(m0 + ty) * K_DIM + k0 + tx];
        sW[ty][tx] = ((float)q[(size_t)o * K_DIM + k0 + tx] - z) * s;
        __syncthreads();
#pragma unroll
        for (int kk = 0; kk < 16; ++kk) acc += sX[ty][kk] * sW[tx][kk];
        __syncthreads();
    }
    C[(size_t)(m0 + ty) * N_DIM + n0 + tx] = acc + bias[n0 + tx];
}

extern "C" void kernel_launch(void* const* d_in, const int* in_sizes, int n_in,
                              void* d_out, int out_size, void* d_ws, size_t ws_size,
                              hipStream_t stream) {
    const float* x    = (const float*)d_in[0];
    const int*   qw   = (const int*)d_in[1];
    const float* sc   = (const float*)d_in[2];
    const float* zp   = (const float*)d_in[3];
    const float* bias = (const float*)d_in[4];
    float* out = (float*)d_out;

    const size_t xb_bytes = (size_t)M_DIM * K_DIM * 2;
    const size_t wb_bytes = (size_t)N_DIM * K_DIM * 2;
    if (ws_size >= xb_bytes + wb_bytes) {
        unsigned short* xb = (unsigned short*)d_ws;
        unsigned short* wb = xb + (size_t)M_DIM * K_DIM;
        k_cvt_x<<<(M_DIM * K_DIM / 8) / 256, 256, 0, stream>>>((const float4*)x, (uint4*)xb);
        k_deq<<<(N_DIM * K_DIM / 8) / 256, 256, 0, stream>>>((const int4*)qw, sc, zp, (uint4*)wb);
        k_gemm<<<(M_DIM / 256) * (N_DIM / 256), 512, 0, stream>>>(xb, wb, bias, out);
    } else {
        dim3 g(N_DIM / 16, M_DIM / 16);
        k_fb<<<g, 256, 0, stream>>>(x, qw, sc, zp, bias, out);
    }
}